// Round 9
// baseline (349.795 us; speedup 1.0000x reference)
//
#include <hip/hip_runtime.h>
#include <math.h>

typedef __attribute__((ext_vector_type(8))) _Float16 fp16x8;
typedef __attribute__((ext_vector_type(4))) _Float16 fp16x4;
typedef __attribute__((ext_vector_type(2))) __fp16 hfp16x2;
typedef __attribute__((ext_vector_type(4))) __fp16 hfp16x4;
typedef __attribute__((ext_vector_type(4))) float floatx4;

#define HID 512
#define TRIC 78
#define OUTC 79
#define BATCH 262144
#define ROWS 128          // batch rows per block; W2 stream amortized 2x vs 64
#define HPAD 520          // halfs/row: stride 1040 B = 260 dwords ≡ 4 (mod 32) -> uniform banks
#define OPAD 84           // floats/row of L tile (84*4 B, 16B-aligned rows)
#define XPAD 24           // halfs/row of x stage
#define X_OFF 66560       // half offset of x region (= 128*520)

// ws layout in halfs (A-frags of the transposed GEMMs; lane map A[c=l&15][k=q*8+j]):
#define W2P_OFF 16384
#define W3P_OFF 278528

__global__ __launch_bounds__(256) void prep_kernel(const float* __restrict__ W1,
                                                   const float* __restrict__ W2,
                                                   const float* __restrict__ W3,
                                                   _Float16* __restrict__ wsh) {
  int g = blockIdx.x * 256 + threadIdx.x;
  int lane = g & 63;
  int l15 = lane & 15, q = lane >> 4;
  fp16x8 v;
  if (g < 2048) {
    int ct = g >> 6;
    int c = ct * 16 + l15;
#pragma unroll
    for (int j = 0; j < 8; ++j) {
      int k = q * 8 + j;
      v[j] = (k < 12) ? (_Float16)W1[k * HID + c] : (_Float16)0.f;
    }
    *(fp16x8*)(wsh + (size_t)g * 8) = v;
  } else if (g < 34816) {
    int h = g - 2048;
    int fk = h >> 6;                 // fk = ct*16 + kb
    int kb = fk & 15, ct = fk >> 4;
    int c = ct * 16 + l15;
    int kbase = kb * 32 + q * 8;
#pragma unroll
    for (int j = 0; j < 8; ++j) v[j] = (_Float16)W2[(kbase + j) * HID + c];
    *(fp16x8*)(wsh + W2P_OFF + (size_t)h * 8) = v;
  } else if (g < 39936) {
    int h = g - 34816;
    int fk = h >> 6;
    int kb = fk & 15, ct = fk >> 4;
    int c = ct * 16 + l15;
    int kbase = kb * 32 + q * 8;
#pragma unroll
    for (int j = 0; j < 8; ++j)
      v[j] = (c < OUTC) ? (_Float16)W3[(kbase + j) * OUTC + c] : (_Float16)0.f;
    *(fp16x8*)(wsh + W3P_OFF + (size_t)h * 8) = v;
  }
}

// fast softplus: v_exp_f32/v_log_f32 paths. abs error ~1e-7 — invisible vs fp16-h error.
__device__ __forceinline__ float softplus_f(float v) {
  float e = __expf(-fabsf(v));
  return fmaxf(v, 0.f) + __logf(1.f + e);
}

// relu + packed f32->f16 convert: 4 v_max_f32 + 2 v_cvt_pkrtz_f16_f32 per 4 values.
__device__ __forceinline__ fp16x4 relu_pk4(floatx4 a) {
  hfp16x2 lo = __builtin_amdgcn_cvt_pkrtz(fmaxf(a[0], 0.f), fmaxf(a[1], 0.f));
  hfp16x2 hi = __builtin_amdgcn_cvt_pkrtz(fmaxf(a[2], 0.f), fmaxf(a[3], 0.f));
  hfp16x4 r = __builtin_shufflevector(lo, hi, 0, 1, 2, 3);
  return __builtin_bit_cast(fp16x4, r);
}

// 1024 threads (16 waves), 128 batch rows/block, 1 block/CU (LDS 139264 B).
__global__ __launch_bounds__(1024, 4) void fused_kernel(const float* __restrict__ x,
                                                        const float* __restrict__ b1,
                                                        const float* __restrict__ b2,
                                                        const float* __restrict__ b3,
                                                        const _Float16* __restrict__ wsh,
                                                        float* __restrict__ out) {
  __shared__ __align__(16) _Float16 hbuf[X_OFF + ROWS * XPAD];  // 139264 B
  const int tid = threadIdx.x;
  const int wave = tid >> 6, lane = tid & 63;  // wave 0..15
  const int l15 = lane & 15, quad = lane >> 4;
  const int r0 = blockIdx.x * ROWS;

  const fp16x8* w1p = (const fp16x8*)wsh;
  const fp16x8* w2p = (const fp16x8*)(wsh + W2P_OFF);
  const fp16x8* w3p = (const fp16x8*)(wsh + W3P_OFF);

  // ---- stage x tile -> fp16 [128][XPAD] (cols 12..15 zeroed; 16..23 never read) ----
  {
    _Float16* xs = hbuf + X_OFF;
    const float* xg = x + (size_t)r0 * 12;
    {
      int row = tid / 12, col = tid - row * 12;       // e = tid (0..1023)
      xs[row * XPAD + col] = (_Float16)xg[tid];
    }
    if (tid < 512) {
      int e = 1024 + tid;                              // e = 1024..1535
      int row = e / 12, col = e - row * 12;
      xs[row * XPAD + col] = (_Float16)xg[e];
      xs[(tid >> 2) * XPAD + 12 + (tid & 3)] = (_Float16)0.f;  // zero cols 12..15, rows 0..127
    }
  }
  // prefetch W1 a-frags before the barrier (drain completes them by loop entry)
  fp16x8 a1p[2];
#pragma unroll
  for (int ct = 0; ct < 2; ++ct) a1p[ct] = w1p[(wave * 2 + ct) * 64 + lane];
  __syncthreads();

  fp16x8 zf;
#pragma unroll
  for (int j = 0; j < 8; ++j) zf[j] = (_Float16)0.f;

  // bias-init accumulators: wave owns 32 h-cols (ct 0..1), 128 rows (nt 0..7)
  floatx4 acc[2][8];  // D: batch-row = nt*16 + l15, c = wave*32 + ct*16 + quad*4+r
#pragma unroll
  for (int ct = 0; ct < 2; ++ct) {
    floatx4 bqc = *(const floatx4*)(b1 + wave * 32 + ct * 16 + quad * 4);
#pragma unroll
    for (int nt = 0; nt < 8; ++nt) acc[ct][nt] = bqc;
  }

  // ---- layer1: h1ᵀ = W1ᵀ xᵀ ----
  {
    const _Float16* xs = hbuf + X_OFF;
#pragma unroll
    for (int nt = 0; nt < 8; ++nt) {
      fp16x8 xb = (quad < 2) ? *(const fp16x8*)(xs + (nt * 16 + l15) * XPAD + quad * 8) : zf;
      acc[0][nt] = __builtin_amdgcn_mfma_f32_16x16x32_f16(a1p[0], xb, acc[0][nt], 0, 0, 0);
      acc[1][nt] = __builtin_amdgcn_mfma_f32_16x16x32_f16(a1p[1], xb, acc[1][nt], 0, 0, 0);
    }
  }

  // ---- epilogue1: relu -> row-major h fp16 (bias already in acc; x region disjoint) ----
#pragma unroll
  for (int ct = 0; ct < 2; ++ct)
#pragma unroll
    for (int nt = 0; nt < 8; ++nt)
      *(fp16x4*)(hbuf + (nt * 16 + l15) * HPAD + wave * 32 + ct * 16 + quad * 4) =
          relu_pk4(acc[ct][nt]);
  // 1-deep prefetch: kb=0 a-frags issued before the barrier (drain completes them)
  fp16x8 ap[2];
#pragma unroll
  for (int ct = 0; ct < 2; ++ct) ap[ct] = w2p[((wave * 2 + ct) * 16 + 0) * 64 + lane];
  __syncthreads();  // h1 ready

  // ---- layer2: h2ᵀ = W2ᵀ h1ᵀ; no barrier inside K-loop; a-frags prefetched 1 kb ahead ----
#pragma unroll
  for (int ct = 0; ct < 2; ++ct) {
    floatx4 bqc = *(const floatx4*)(b2 + wave * 32 + ct * 16 + quad * 4);
#pragma unroll
    for (int nt = 0; nt < 8; ++nt) acc[ct][nt] = bqc;
  }

#pragma unroll 2
  for (int kb = 0; kb < 16; ++kb) {
    fp16x8 a0 = ap[0], a1v = ap[1];
    const int kbn = (kb + 1) & 15;  // branchless; last iter re-fetches kb=0 (harmless)
    ap[0] = w2p[((wave * 2 + 0) * 16 + kbn) * 64 + lane];
    ap[1] = w2p[((wave * 2 + 1) * 16 + kbn) * 64 + lane];
    __builtin_amdgcn_s_setprio(1);
#pragma unroll
    for (int nt = 0; nt < 8; ++nt) {
      fp16x8 b = *(const fp16x8*)(hbuf + (nt * 16 + l15) * HPAD + kb * 32 + quad * 8);
      acc[0][nt] = __builtin_amdgcn_mfma_f32_16x16x32_f16(a0, b, acc[0][nt], 0, 0, 0);
      acc[1][nt] = __builtin_amdgcn_mfma_f32_16x16x32_f16(a1v, b, acc[1][nt], 0, 0, 0);
    }
    __builtin_amdgcn_s_setprio(0);
  }

  __syncthreads();  // all waves done reading h1

  // ---- epilogue2: relu -> h2 row-major (in place) ----
#pragma unroll
  for (int ct = 0; ct < 2; ++ct)
#pragma unroll
    for (int nt = 0; nt < 8; ++nt)
      *(fp16x4*)(hbuf + (nt * 16 + l15) * HPAD + wave * 32 + ct * 16 + quad * 4) =
          relu_pk4(acc[ct][nt]);

  // ---- layer3: wave pair -> m-tile = wave>>1 (8 m-tiles x 16 rows = 128);
  //      even wave: c-tiles {0,1,2}, odd: {3,4} ----
  const int mt3 = wave >> 1;
  const int codd = wave & 1;
  const int c0 = codd ? 3 : 0;
  const int nct = codd ? 2 : 3;

  floatx4 b3q[3];
#pragma unroll
  for (int j = 0; j < 3; ++j) {
#pragma unroll
    for (int r = 0; r < 4; ++r) {
      int c = (c0 + j) * 16 + quad * 4 + r;
      b3q[j][r] = (j < nct && c < OUTC) ? b3[c] : 0.f;
    }
  }
  floatx4 acc3[3];
#pragma unroll
  for (int j = 0; j < 3; ++j) acc3[j] = b3q[j];

  // 1-deep prefetch of kb=0 W3 a-frags before the barrier
  fp16x8 ap3[3];
#pragma unroll
  for (int j = 0; j < 3; ++j) ap3[j] = zf;
#pragma unroll
  for (int j = 0; j < 3; ++j)
    if (j < nct) ap3[j] = w3p[((c0 + j) * 16 + 0) * 64 + lane];
  __syncthreads();  // h2 ready

#pragma unroll 2
  for (int kb = 0; kb < 16; ++kb) {
    fp16x8 bfrag = *(const fp16x8*)(hbuf + (mt3 * 16 + l15) * HPAD + kb * 32 + quad * 8);
    fp16x8 a3[3];
#pragma unroll
    for (int j = 0; j < 3; ++j) a3[j] = ap3[j];
    const int kbn = (kb + 1) & 15;
#pragma unroll
    for (int j = 0; j < 3; ++j)
      if (j < nct) ap3[j] = w3p[((c0 + j) * 16 + kbn) * 64 + lane];
    __builtin_amdgcn_s_setprio(1);
#pragma unroll
    for (int j = 0; j < 3; ++j)
      if (j < nct)
        acc3[j] = __builtin_amdgcn_mfma_f32_16x16x32_f16(a3[j], bfrag, acc3[j], 0, 0, 0);
    __builtin_amdgcn_s_setprio(0);
  }
  __syncthreads();  // all waves done reading h2

  // ---- epilogue3: softplus -> L tile [128][OPAD] fp32 at LDS base (43008 B, h region dead);
  //      c column (col 78 = acc3[1][2] of odd-wave quad==3 lanes) stored direct ----
  float* outf = (float*)hbuf;
#pragma unroll
  for (int j = 0; j < 3; ++j)
    if (j < nct) {
      floatx4 v;
#pragma unroll
      for (int r = 0; r < 4; ++r) v[r] = softplus_f(acc3[j][r]);
      *(floatx4*)(outf + (mt3 * 16 + l15) * OPAD + (c0 + j) * 16 + quad * 4) = v;
    }
  if (codd && quad == 3)
    out[(size_t)BATCH * 144 + r0 + mt3 * 16 + l15] = softplus_f(acc3[1][2]);
  __syncthreads();

  // ---- MMT: register-resident L row (20x b128 broadcast reads, const-indexed),
  //      8 threads/row (1024 thr / 128 rows); thread owns cols {sub, sub+8(sub<4)};
  //      direct global stores ----
  {
    const float* Lbase = (const float*)hbuf;
    const int rowl = tid >> 3;   // 0..127
    const int sub = tid & 7;
    const float* Lr = Lbase + rowl * OPAD;  // 16B-aligned (OPAD*4 = 336 = 21*16)

    // full tri row -> registers; all later Li indices are compile-time constants
    float R[80];
#pragma unroll
    for (int q = 0; q < 20; ++q) {
      floatx4 v = *(const floatx4*)(Lr + q * 4);
#pragma unroll
      for (int r = 0; r < 4; ++r) R[q * 4 + r] = v[r];
    }

    // thread-dependent columns fetched once from LDS (dynamic addr is fine there)
    float Lj0[12], Lj1[12];
    {
      const int tj = (sub * (sub + 1)) >> 1;
#pragma unroll
      for (int k = 0; k < 12; ++k) Lj0[k] = (k <= sub) ? Lr[tj + k] : 0.f;
#pragma unroll
      for (int k = 0; k < 12; ++k) Lj1[k] = 0.f;
      const int j1 = sub + 8;
      if (sub < 4) {
        const int tj1 = (j1 * (j1 + 1)) >> 1;
#pragma unroll
        for (int k = 0; k < 12; ++k) Lj1[k] = (k <= j1) ? Lr[tj1 + k] : 0.f;
      }
    }

    // direct global stores: 8 threads jointly cover the 576B row in-window -> L2 merges
    float* Mg = out + ((size_t)r0 + rowl) * 144;
#pragma unroll
    for (int i = 0; i < 12; ++i) {
      const int ti = (i * (i + 1)) >> 1;
      float s0 = 0.f, s1 = 0.f;
#pragma unroll
      for (int k = 0; k <= i; ++k) {
        const float li = R[ti + k];        // constant index -> stays in VGPR
        s0 = fmaf(li, Lj0[k], s0);
        s1 = fmaf(li, Lj1[k], s1);         // interleaved chains: ILP 2
      }
      Mg[i * 12 + sub] = s0;
      if (sub < 4) Mg[i * 12 + sub + 8] = s1;
    }
  }
}

extern "C" void kernel_launch(void* const* d_in, const int* in_sizes, int n_in,
                              void* d_out, int out_size, void* d_ws, size_t ws_size,
                              hipStream_t stream) {
  const float* x  = (const float*)d_in[0];
  const float* W1 = (const float*)d_in[1];
  const float* b1 = (const float*)d_in[2];
  const float* W2 = (const float*)d_in[3];
  const float* b2 = (const float*)d_in[4];
  const float* W3 = (const float*)d_in[5];
  const float* b3 = (const float*)d_in[6];
  float* out = (float*)d_out;
  _Float16* wsh = (_Float16*)d_ws;

  prep_kernel<<<156, 256, 0, stream>>>(W1, W2, W3, wsh);
  fused_kernel<<<BATCH / ROWS, 1024, 0, stream>>>(x, b1, b2, b3, wsh, out);
}

// Round 10
// 332.043 us; speedup vs baseline: 1.0535x; 1.0535x over previous
//
#include <hip/hip_runtime.h>
#include <math.h>

typedef __attribute__((ext_vector_type(8))) _Float16 fp16x8;
typedef __attribute__((ext_vector_type(4))) _Float16 fp16x4;
typedef __attribute__((ext_vector_type(2))) __fp16 hfp16x2;
typedef __attribute__((ext_vector_type(4))) __fp16 hfp16x4;
typedef __attribute__((ext_vector_type(4))) float floatx4;

#define HID 512
#define TRIC 78
#define OUTC 79
#define BATCH 262144
#define HPAD 520          // halfs/row: stride 1040 B = 260 dwords ≡ 4 (mod 32) -> uniform banks
#define LPAD 88           // halfs/row of fp16 L tile: 44 dwords ≡ 12 (mod 32) -> 8 rows, 8 banks
#define XPAD 24           // halfs/row of x stage
#define X_OFF 33280       // half offset of x region (= 64*520)

// ws layout in halfs (A-frags of the transposed GEMMs; lane map A[c=l&15][k=q*8+j]):
#define W2P_OFF 16384
#define W3P_OFF 278528

__global__ __launch_bounds__(256) void prep_kernel(const float* __restrict__ W1,
                                                   const float* __restrict__ W2,
                                                   const float* __restrict__ W3,
                                                   _Float16* __restrict__ wsh) {
  int g = blockIdx.x * 256 + threadIdx.x;
  int lane = g & 63;
  int l15 = lane & 15, q = lane >> 4;
  fp16x8 v;
  if (g < 2048) {
    int ct = g >> 6;
    int c = ct * 16 + l15;
#pragma unroll
    for (int j = 0; j < 8; ++j) {
      int k = q * 8 + j;
      v[j] = (k < 12) ? (_Float16)W1[k * HID + c] : (_Float16)0.f;
    }
    *(fp16x8*)(wsh + (size_t)g * 8) = v;
  } else if (g < 34816) {
    int h = g - 2048;
    int fk = h >> 6;                 // fk = ct*16 + kb
    int kb = fk & 15, ct = fk >> 4;
    int c = ct * 16 + l15;
    int kbase = kb * 32 + q * 8;
#pragma unroll
    for (int j = 0; j < 8; ++j) v[j] = (_Float16)W2[(kbase + j) * HID + c];
    *(fp16x8*)(wsh + W2P_OFF + (size_t)h * 8) = v;
  } else if (g < 39936) {
    int h = g - 34816;
    int fk = h >> 6;
    int kb = fk & 15, ct = fk >> 4;
    int c = ct * 16 + l15;
    int kbase = kb * 32 + q * 8;
#pragma unroll
    for (int j = 0; j < 8; ++j)
      v[j] = (c < OUTC) ? (_Float16)W3[(kbase + j) * OUTC + c] : (_Float16)0.f;
    *(fp16x8*)(wsh + W3P_OFF + (size_t)h * 8) = v;
  }
}

// fast softplus: v_exp_f32/v_log_f32 paths. abs error ~1e-7 — invisible vs fp16-h error.
__device__ __forceinline__ float softplus_f(float v) {
  float e = __expf(-fabsf(v));
  return fmaxf(v, 0.f) + __logf(1.f + e);
}

// relu + packed f32->f16 convert: 4 v_max_f32 + 2 v_cvt_pkrtz_f16_f32 per 4 values.
__device__ __forceinline__ fp16x4 relu_pk4(floatx4 a) {
  hfp16x2 lo = __builtin_amdgcn_cvt_pkrtz(fmaxf(a[0], 0.f), fmaxf(a[1], 0.f));
  hfp16x2 hi = __builtin_amdgcn_cvt_pkrtz(fmaxf(a[2], 0.f), fmaxf(a[3], 0.f));
  hfp16x4 r = __builtin_shufflevector(lo, hi, 0, 1, 2, 3);
  return __builtin_bit_cast(fp16x4, r);
}

// packed f32x4 -> f16x4 (no relu; softplus output is >= 0 already)
__device__ __forceinline__ fp16x4 pk4(floatx4 a) {
  hfp16x2 lo = __builtin_amdgcn_cvt_pkrtz(a[0], a[1]);
  hfp16x2 hi = __builtin_amdgcn_cvt_pkrtz(a[2], a[3]);
  hfp16x4 r = __builtin_shufflevector(lo, hi, 0, 1, 2, 3);
  return __builtin_bit_cast(fp16x4, r);
}

__global__ __launch_bounds__(512, 4) void fused_kernel(const float* __restrict__ x,
                                                       const float* __restrict__ b1,
                                                       const float* __restrict__ b2,
                                                       const float* __restrict__ b3,
                                                       const _Float16* __restrict__ wsh,
                                                       float* __restrict__ out) {
  __shared__ __align__(16) _Float16 hbuf[X_OFF + 64 * XPAD];  // 68 KB
  const int tid = threadIdx.x;
  const int wave = tid >> 6, lane = tid & 63;
  const int l15 = lane & 15, quad = lane >> 4;
  const int r0 = blockIdx.x * 64;

  const fp16x8* w1p = (const fp16x8*)wsh;
  const fp16x8* w2p = (const fp16x8*)(wsh + W2P_OFF);
  const fp16x8* w3p = (const fp16x8*)(wsh + W3P_OFF);

  // ---- stage x tile -> fp16 [64][XPAD] (cols 12..15 zeroed; 16..23 never read) ----
  {
    _Float16* xs = hbuf + X_OFF;
    const float* xg = x + (size_t)r0 * 12;
    if (tid < 256) {
      int e = 512 + tid;
      int row = e / 12, col = e - row * 12;
      xs[row * XPAD + col] = (_Float16)xg[e];
      xs[(tid >> 2) * XPAD + 12 + (tid & 3)] = (_Float16)0.f;
    }
    {
      int row = tid / 12, col = tid - row * 12;
      xs[row * XPAD + col] = (_Float16)xg[tid];
    }
  }
  // prefetch W1 a-frags before the barrier (drain completes them by loop entry)
  fp16x8 a1p[4];
#pragma unroll
  for (int ct = 0; ct < 4; ++ct) a1p[ct] = w1p[(wave * 4 + ct) * 64 + lane];
  __syncthreads();

  fp16x8 zf;
#pragma unroll
  for (int j = 0; j < 8; ++j) zf[j] = (_Float16)0.f;

  // bias-init accumulators: MFMA C-in starts at the bias (same for all batch tiles).
  floatx4 bq[4];
#pragma unroll
  for (int ct = 0; ct < 4; ++ct)
    bq[ct] = *(const floatx4*)(b1 + wave * 64 + ct * 16 + quad * 4);

  floatx4 acc[4][4];  // [c-tile][batch-tile]; D: batch-row = l15, c = quad*4+r
#pragma unroll
  for (int ct = 0; ct < 4; ++ct)
#pragma unroll
    for (int nt = 0; nt < 4; ++nt) acc[ct][nt] = bq[ct];

  // ---- layer1: h1ᵀ = W1ᵀ xᵀ. Wave owns 64 h-cols (ct 0..3), all 64 rows ----
  {
    const _Float16* xs = hbuf + X_OFF;
    fp16x8 xb[4];
#pragma unroll
    for (int nt = 0; nt < 4; ++nt)
      xb[nt] = (quad < 2) ? *(const fp16x8*)(xs + (nt * 16 + l15) * XPAD + quad * 8) : zf;
#pragma unroll
    for (int ct = 0; ct < 4; ++ct) {
#pragma unroll
      for (int nt = 0; nt < 4; ++nt)
        acc[ct][nt] = __builtin_amdgcn_mfma_f32_16x16x32_f16(a1p[ct], xb[nt], acc[ct][nt], 0, 0, 0);
    }
  }

  // ---- epilogue1: relu -> row-major h fp16 (bias already in acc; x region disjoint) ----
#pragma unroll
  for (int ct = 0; ct < 4; ++ct)
#pragma unroll
    for (int nt = 0; nt < 4; ++nt)
      *(fp16x4*)(hbuf + (nt * 16 + l15) * HPAD + wave * 64 + ct * 16 + quad * 4) =
          relu_pk4(acc[ct][nt]);
  // 1-deep prefetch: kb=0 a-frags issued before the barrier (drain completes them)
  fp16x8 ap[4];
#pragma unroll
  for (int ct = 0; ct < 4; ++ct) ap[ct] = w2p[((wave * 4 + ct) * 16 + 0) * 64 + lane];
  __syncthreads();  // h1 ready

  // ---- layer2: h2ᵀ = W2ᵀ h1ᵀ; no barrier inside K-loop; a-frags prefetched 1 kb ahead ----
#pragma unroll
  for (int ct = 0; ct < 4; ++ct)
    bq[ct] = *(const floatx4*)(b2 + wave * 64 + ct * 16 + quad * 4);
#pragma unroll
  for (int ct = 0; ct < 4; ++ct)
#pragma unroll
    for (int nt = 0; nt < 4; ++nt) acc[ct][nt] = bq[ct];

#pragma unroll 2
  for (int kb = 0; kb < 16; ++kb) {
    fp16x8 a[4], b[4];
#pragma unroll
    for (int ct = 0; ct < 4; ++ct) a[ct] = ap[ct];
#pragma unroll
    for (int nt = 0; nt < 4; ++nt)
      b[nt] = *(const fp16x8*)(hbuf + (nt * 16 + l15) * HPAD + kb * 32 + quad * 8);
    const int kbn = (kb + 1) & 15;  // branchless; last iter re-fetches kb=0 (harmless)
#pragma unroll
    for (int ct = 0; ct < 4; ++ct) ap[ct] = w2p[((wave * 4 + ct) * 16 + kbn) * 64 + lane];
    __builtin_amdgcn_s_setprio(1);
#pragma unroll
    for (int ct = 0; ct < 4; ++ct)
#pragma unroll
      for (int nt = 0; nt < 4; ++nt)
        acc[ct][nt] = __builtin_amdgcn_mfma_f32_16x16x32_f16(a[ct], b[nt], acc[ct][nt], 0, 0, 0);
    __builtin_amdgcn_s_setprio(0);
  }

  __syncthreads();  // all waves done reading h1

  // ---- epilogue2: relu -> h2 row-major (in place) ----
#pragma unroll
  for (int ct = 0; ct < 4; ++ct)
#pragma unroll
    for (int nt = 0; nt < 4; ++nt)
      *(fp16x4*)(hbuf + (nt * 16 + l15) * HPAD + wave * 64 + ct * 16 + quad * 4) =
          relu_pk4(acc[ct][nt]);

  // ---- layer3 setup: wave -> m-tile = wave>>1; even wave: c-tiles {0,1,2}, odd: {3,4} ----
  const int mt3 = wave >> 1;
  const int codd = wave & 1;
  const int c0 = codd ? 3 : 0;
  const int nct = codd ? 2 : 3;

  floatx4 b3q[3];
#pragma unroll
  for (int j = 0; j < 3; ++j) {
#pragma unroll
    for (int r = 0; r < 4; ++r) {
      int c = (c0 + j) * 16 + quad * 4 + r;
      b3q[j][r] = (j < nct && c < OUTC) ? b3[c] : 0.f;
    }
  }
  floatx4 acc3[3];
#pragma unroll
  for (int j = 0; j < 3; ++j) acc3[j] = b3q[j];

  // 1-deep prefetch of kb=0 W3 a-frags before the barrier
  fp16x8 ap3[3];
#pragma unroll
  for (int j = 0; j < 3; ++j) ap3[j] = zf;
#pragma unroll
  for (int j = 0; j < 3; ++j)
    if (j < nct) ap3[j] = w3p[((c0 + j) * 16 + 0) * 64 + lane];
  __syncthreads();  // h2 ready

  // b-frag also prefetched 1 kb ahead (acc dead here -> registers free, under layer2 peak)
  fp16x8 bp3 = *(const fp16x8*)(hbuf + (mt3 * 16 + l15) * HPAD + 0 * 32 + quad * 8);
#pragma unroll 2
  for (int kb = 0; kb < 16; ++kb) {
    fp16x8 bfrag = bp3;
    fp16x8 a3[3];
#pragma unroll
    for (int j = 0; j < 3; ++j) a3[j] = ap3[j];
    const int kbn = (kb + 1) & 15;
    bp3 = *(const fp16x8*)(hbuf + (mt3 * 16 + l15) * HPAD + kbn * 32 + quad * 8);
#pragma unroll
    for (int j = 0; j < 3; ++j)
      if (j < nct) ap3[j] = w3p[((c0 + j) * 16 + kbn) * 64 + lane];
    __builtin_amdgcn_s_setprio(1);
#pragma unroll
    for (int j = 0; j < 3; ++j)
      if (j < nct)
        acc3[j] = __builtin_amdgcn_mfma_f32_16x16x32_f16(a3[j], bfrag, acc3[j], 0, 0, 0);
    __builtin_amdgcn_s_setprio(0);
  }
  __syncthreads();  // all waves done reading h2

  // ---- epilogue3: softplus -> fp16 L tile [64][LPAD] at LDS base (h region dead);
  //      c column (col 78 = acc3[1][2] of odd-wave quad==3 lanes) stored direct ----
#pragma unroll
  for (int j = 0; j < 3; ++j)
    if (j < nct) {
      floatx4 v;
#pragma unroll
      for (int r = 0; r < 4; ++r) v[r] = softplus_f(acc3[j][r]);
      *(fp16x4*)(hbuf + (mt3 * 16 + l15) * LPAD + (c0 + j) * 16 + quad * 4) = pk4(v);
    }
  if (codd && quad == 3)
    out[(size_t)BATCH * 144 + r0 + mt3 * 16 + l15] = softplus_f(acc3[1][2]);
  __syncthreads();

  // ---- MMT: register-resident L row (10x b128 broadcast reads, bank-exact, const-indexed),
  //      8 threads/row; thread owns cols {sub, sub+8(sub<4)}; direct global stores ----
  {
    const int rowl = tid >> 3;
    const int sub = tid & 7;
    const _Float16* Lr = hbuf + rowl * LPAD;  // 16B-aligned (LPAD*2 = 176 = 11*16)

    // full tri row -> f32 registers; all later Li indices are compile-time constants
    float R[80];
#pragma unroll
    for (int q = 0; q < 10; ++q) {
      fp16x8 v = *(const fp16x8*)(Lr + q * 8);
#pragma unroll
      for (int r = 0; r < 8; ++r) R[q * 8 + r] = (float)v[r];
    }

    // thread-dependent columns fetched once from LDS (dynamic addr is fine there)
    float Lj0[12], Lj1[12];
    {
      const int tj = (sub * (sub + 1)) >> 1;
#pragma unroll
      for (int k = 0; k < 12; ++k) Lj0[k] = (k <= sub) ? (float)Lr[tj + k] : 0.f;
#pragma unroll
      for (int k = 0; k < 12; ++k) Lj1[k] = 0.f;
      const int j1 = sub + 8;
      if (sub < 4) {
        const int tj1 = (j1 * (j1 + 1)) >> 1;
#pragma unroll
        for (int k = 0; k < 12; ++k) Lj1[k] = (k <= j1) ? (float)Lr[tj1 + k] : 0.f;
      }
    }

    // direct global stores: 8 threads jointly cover the 576B row in-window -> L2 merges
    float* Mg = out + ((size_t)r0 + rowl) * 144;
#pragma unroll
    for (int i = 0; i < 12; ++i) {
      const int ti = (i * (i + 1)) >> 1;
      float s0 = 0.f, s1 = 0.f;
#pragma unroll
      for (int k = 0; k <= i; ++k) {
        const float li = R[ti + k];        // constant index -> stays in VGPR
        s0 = fmaf(li, Lj0[k], s0);
        s1 = fmaf(li, Lj1[k], s1);         // interleaved chains: ILP 2
      }
      Mg[i * 12 + sub] = s0;
      if (sub < 4) Mg[i * 12 + sub + 8] = s1;
    }
  }
}

extern "C" void kernel_launch(void* const* d_in, const int* in_sizes, int n_in,
                              void* d_out, int out_size, void* d_ws, size_t ws_size,
                              hipStream_t stream) {
  const float* x  = (const float*)d_in[0];
  const float* W1 = (const float*)d_in[1];
  const float* b1 = (const float*)d_in[2];
  const float* W2 = (const float*)d_in[3];
  const float* b2 = (const float*)d_in[4];
  const float* W3 = (const float*)d_in[5];
  const float* b3 = (const float*)d_in[6];
  float* out = (float*)d_out;
  _Float16* wsh = (_Float16*)d_ws;

  prep_kernel<<<156, 256, 0, stream>>>(W1, W2, W3, wsh);
  fused_kernel<<<BATCH / 64, 512, 0, stream>>>(x, b1, b2, b3, wsh, out);
}